// Round 1
// baseline (488.607 us; speedup 1.0000x reference)
//
#include <hip/hip_runtime.h>
#include <hip/hip_bf16.h>

#define NN      262144    // N = B*WIN_IN*NODES
#define EDGES   2097152
#define FEATD   16
#define HIDD    64
#define LSTMH   32
#define BATCH   64
#define WIN     32
#define WOUT    8
#define NCLS    10
#define ROWD    2048      // NODES*FEAT = B*WIN (both 2048)
#define KCHUNKS 8

// ---- degree: deg[col] += 1 per edge ----
__global__ void k_deg(const int* __restrict__ ei, float* __restrict__ deg) {
    int stride = gridDim.x * blockDim.x;
    for (int e = blockIdx.x * blockDim.x + threadIdx.x; e < EDGES; e += stride)
        atomicAdd(&deg[ei[EDGES + e]], 1.0f);
}

// ---- dinv[i] = rsqrt(deg+1), in place ----
__global__ void k_dinv(float* __restrict__ d) {
    int i = blockIdx.x * blockDim.x + threadIdx.x;
    if (i < NN) d[i] = rsqrtf(d[i] + 1.0f);
}

// ---- edge aggregation: agg[col][f] += src[row][f] * dinv[row]*dinv[col] ----
// thread = (edge, feat): 16 lanes share one edge -> coalesced 64B gather + 16 contiguous atomics
__global__ void k_agg(const int* __restrict__ ei, const float* __restrict__ src,
                      const float* __restrict__ dinv, float* __restrict__ agg) {
    int stride = gridDim.x * blockDim.x;
    const int total = EDGES * FEATD;
    for (int t = blockIdx.x * blockDim.x + threadIdx.x; t < total; t += stride) {
        int e = t >> 4;
        int f = t & 15;
        int r = ei[e];
        int c = ei[EDGES + e];
        float s = dinv[r] * dinv[c];
        atomicAdd(&agg[c * FEATD + f], src[r * FEATD + f] * s);
    }
}

// ---- fused: in = aggX + x*dinv^2 ; hid = relu(in@W1+b1) ; t2 = hid@W2 ----
__global__ void k_gcnmlp(const float* __restrict__ aggX, const float* __restrict__ x,
                         const float* __restrict__ dinv,
                         const float* __restrict__ W1, const float* __restrict__ b1,
                         const float* __restrict__ W2, float* __restrict__ t2) {
    __shared__ float sW1[FEATD * HIDD];
    __shared__ float sW2[HIDD * FEATD];
    __shared__ float sb1[HIDD];
    for (int l = threadIdx.x; l < FEATD * HIDD; l += blockDim.x) {
        sW1[l] = W1[l];
        sW2[l] = W2[l];
    }
    if (threadIdx.x < HIDD) sb1[threadIdx.x] = b1[threadIdx.x];
    __syncthreads();
    int n = blockIdx.x * blockDim.x + threadIdx.x;
    if (n >= NN) return;
    float d2 = dinv[n]; d2 *= d2;
    float in[FEATD];
    const float4* ax = (const float4*)(aggX + (size_t)n * FEATD);
    const float4* xx = (const float4*)(x + (size_t)n * FEATD);
#pragma unroll
    for (int q = 0; q < 4; q++) {
        float4 a = ax[q], b = xx[q];
        in[q * 4 + 0] = a.x + b.x * d2;
        in[q * 4 + 1] = a.y + b.y * d2;
        in[q * 4 + 2] = a.z + b.z * d2;
        in[q * 4 + 3] = a.w + b.w * d2;
    }
    float out[FEATD];
#pragma unroll
    for (int c = 0; c < FEATD; c++) out[c] = 0.f;
#pragma unroll 8
    for (int j = 0; j < HIDD; j++) {
        float h = sb1[j];
#pragma unroll
        for (int f = 0; f < FEATD; f++) h += in[f] * sW1[f * HIDD + j];
        h = fmaxf(h, 0.f);
#pragma unroll
        for (int c = 0; c < FEATD; c++) out[c] += h * sW2[j * FEATD + c];
    }
    float4* o = (float4*)(t2 + (size_t)n * FEATD);
    o[0] = make_float4(out[0], out[1], out[2], out[3]);
    o[1] = make_float4(out[4], out[5], out[6], out[7]);
    o[2] = make_float4(out[8], out[9], out[10], out[11]);
    o[3] = make_float4(out[12], out[13], out[14], out[15]);
}

// ---- h2 = relu(agg2 + t2*dinv^2 + b2), written in place over t2 (float4 over N*16) ----
__global__ void k_combine(const float* __restrict__ agg2, float* __restrict__ t2,
                          const float* __restrict__ dinv, const float* __restrict__ b2) {
    int i = blockIdx.x * blockDim.x + threadIdx.x;   // float4 index, N*4 total
    if (i >= NN * 4) return;
    int node = i >> 2, q = i & 3;
    float d2 = dinv[node]; d2 *= d2;
    float4 a = ((const float4*)agg2)[i];
    float4 t = ((const float4*)t2)[i];
    float4 b = ((const float4*)b2)[q];
    float4 r;
    r.x = fmaxf(a.x + t.x * d2 + b.x, 0.f);
    r.y = fmaxf(a.y + t.y * d2 + b.y, 0.f);
    r.z = fmaxf(a.z + t.z * d2 + b.z, 0.f);
    r.w = fmaxf(a.w + t.w * d2 + b.w, 0.f);
    ((float4*)t2)[i] = r;
}

// ---- LSTM input GEMM: gxp[p][r][j] = sum_{k in chunk p} A[r][k]*Wih[j][k] ----
// A: 2048x2048 (h2), Wih: 128x2048. grid = (32 row-blocks, 8 K-chunks), 256 thr.
#define KT 32
__global__ void k_gemmA(const float* __restrict__ A, const float* __restrict__ Wih,
                        float* __restrict__ gxp) {
    __shared__ float As[64][KT + 1];
    __shared__ float Bs[128][KT + 1];
    int tid = threadIdx.x;
    int tx = tid & 15, ty = tid >> 4;
    float acc[4][8];
#pragma unroll
    for (int i = 0; i < 4; i++)
#pragma unroll
        for (int j = 0; j < 8; j++) acc[i][j] = 0.f;
    int row0 = blockIdx.x * 64;
    int k0 = blockIdx.y * (ROWD / KCHUNKS);
    for (int kk = 0; kk < ROWD / KCHUNKS; kk += KT) {
        for (int l = tid; l < 64 * KT / 4; l += 256) {
            int rr = l >> 3;
            int cc = (l & 7) * 4;
            float4 v = *(const float4*)&A[(size_t)(row0 + rr) * ROWD + k0 + kk + cc];
            As[rr][cc + 0] = v.x; As[rr][cc + 1] = v.y; As[rr][cc + 2] = v.z; As[rr][cc + 3] = v.w;
        }
        for (int l = tid; l < 128 * KT / 4; l += 256) {
            int rr = l >> 3;
            int cc = (l & 7) * 4;
            float4 v = *(const float4*)&Wih[(size_t)rr * ROWD + k0 + kk + cc];
            Bs[rr][cc + 0] = v.x; Bs[rr][cc + 1] = v.y; Bs[rr][cc + 2] = v.z; Bs[rr][cc + 3] = v.w;
        }
        __syncthreads();
#pragma unroll
        for (int k = 0; k < KT; k++) {
            float a[4], b[8];
#pragma unroll
            for (int i = 0; i < 4; i++) a[i] = As[ty * 4 + i][k];
#pragma unroll
            for (int j = 0; j < 8; j++) b[j] = Bs[tx * 8 + j][k];
#pragma unroll
            for (int i = 0; i < 4; i++)
#pragma unroll
                for (int j = 0; j < 8; j++) acc[i][j] += a[i] * b[j];
        }
        __syncthreads();
    }
    float* out = gxp + (size_t)blockIdx.y * (ROWD * 128);
#pragma unroll
    for (int i = 0; i < 4; i++)
#pragma unroll
        for (int j = 0; j < 8; j++)
            out[(size_t)(row0 + ty * 4 + i) * 128 + tx * 8 + j] = acc[i][j];
}

// ---- LSTM recurrence: one block per batch element, 128 threads (one per gate unit) ----
__global__ void k_lstm(const float* __restrict__ gxp, const float* __restrict__ Whh,
                       const float* __restrict__ bih, const float* __restrict__ bhh,
                       float* __restrict__ hseq) {
    __shared__ float sWhhT[LSTMH][4 * LSTMH];   // [k][j] = Whh[j][k]
    __shared__ float sh[LSTMH], sc[LSTMH], sg[4 * LSTMH];
    int b = blockIdx.x, j = threadIdx.x;
    for (int l = j; l < 4 * LSTMH * LSTMH; l += 4 * LSTMH) {
        int r = l >> 5, k = l & 31;
        sWhhT[k][r] = Whh[l];
    }
    float bias = bih[j] + bhh[j];
    if (j < LSTMH) { sh[j] = 0.f; sc[j] = 0.f; }
    __syncthreads();
    for (int t = 0; t < WIN; t++) {
        const float* g0 = gxp + (size_t)(b * WIN + t) * 128 + j;
        float g = bias;
#pragma unroll
        for (int p = 0; p < KCHUNKS; p++) g += g0[(size_t)p * ROWD * 128];
#pragma unroll
        for (int k = 0; k < LSTMH; k++) g += sWhhT[k][j] * sh[k];
        sg[j] = g;
        __syncthreads();
        if (j < LSTMH) {
            float ig = sg[j], fg = sg[32 + j], gg = sg[64 + j], og = sg[96 + j];
            float c = sc[j];
            float si = 1.f / (1.f + __expf(-ig));
            float sf = 1.f / (1.f + __expf(-fg));
            float so = 1.f / (1.f + __expf(-og));
            c = sf * c + si * tanhf(gg);
            float h = so * tanhf(c);
            sc[j] = c; sh[j] = h;
            if (t >= WIN - WOUT)
                hseq[(size_t)(b * WOUT + (t - (WIN - WOUT))) * LSTMH + j] = h;
        }
        __syncthreads();
    }
}

// ---- FC head: (512 rows) 32 -> 16 relu -> 10 ----
__global__ void k_fc(const float* __restrict__ hseq, const float* __restrict__ Wfc1,
                     const float* __restrict__ bfc1, const float* __restrict__ Wfc2,
                     const float* __restrict__ bfc2, float* __restrict__ out) {
    __shared__ float sW1[16 * 32], sb1[16], sW2[10 * 16], sb2[10];
    int tid = threadIdx.x;
    for (int l = tid; l < 16 * 32; l += blockDim.x) sW1[l] = Wfc1[l];
    if (tid < 16) sb1[tid] = bfc1[tid];
    for (int l = tid; l < 160; l += blockDim.x) sW2[l] = Wfc2[l];
    if (tid < 10) sb2[tid] = bfc2[tid];
    __syncthreads();
    int r = blockIdx.x * blockDim.x + tid;
    if (r >= BATCH * WOUT) return;
    float h[32];
#pragma unroll
    for (int k = 0; k < 32; k++) h[k] = hseq[(size_t)r * 32 + k];
    float hid[16];
#pragma unroll
    for (int j = 0; j < 16; j++) {
        float v = sb1[j];
#pragma unroll
        for (int k = 0; k < 32; k++) v += sW1[j * 32 + k] * h[k];
        hid[j] = fmaxf(v, 0.f);
    }
#pragma unroll
    for (int c = 0; c < NCLS; c++) {
        float v = sb2[c];
#pragma unroll
        for (int j = 0; j < 16; j++) v += sW2[c * 16 + j] * hid[j];
        out[(size_t)r * NCLS + c] = v;
    }
}

extern "C" void kernel_launch(void* const* d_in, const int* in_sizes, int n_in,
                              void* d_out, int out_size, void* d_ws, size_t ws_size,
                              hipStream_t stream) {
    const float* x    = (const float*)d_in[0];
    const int*   ei   = (const int*)d_in[1];
    const float* W1   = (const float*)d_in[2];
    const float* b1   = (const float*)d_in[3];
    const float* W2   = (const float*)d_in[4];
    const float* b2   = (const float*)d_in[5];
    const float* Wih  = (const float*)d_in[6];
    const float* Whh  = (const float*)d_in[7];
    const float* bih  = (const float*)d_in[8];
    const float* bhh  = (const float*)d_in[9];
    const float* Wfc1 = (const float*)d_in[10];
    const float* bfc1 = (const float*)d_in[11];
    const float* Wfc2 = (const float*)d_in[12];
    const float* bfc2 = (const float*)d_in[13];
    float* out = (float*)d_out;

    float* ws   = (float*)d_ws;
    float* dinv = ws;                         // N
    float* agg  = dinv + NN;                  // N*16  (aggX, then reused as agg2)
    float* t2   = agg + (size_t)NN * FEATD;   // N*16  (t2, then h2 in place)
    float* gxp  = t2 + (size_t)NN * FEATD;    // 8 * 2048 * 128
    float* hseq = gxp + (size_t)KCHUNKS * ROWD * 128;  // 64*8*32

    // zero deg + aggX (contiguous)
    hipMemsetAsync(dinv, 0, (size_t)(NN + NN * FEATD) * sizeof(float), stream);
    k_deg<<<2048, 256, 0, stream>>>(ei, dinv);
    k_dinv<<<NN / 256, 256, 0, stream>>>(dinv);
    k_agg<<<8192, 256, 0, stream>>>(ei, x, dinv, agg);
    k_gcnmlp<<<NN / 256, 256, 0, stream>>>(agg, x, dinv, W1, b1, W2, t2);
    hipMemsetAsync(agg, 0, (size_t)NN * FEATD * sizeof(float), stream);
    k_agg<<<8192, 256, 0, stream>>>(ei, t2, dinv, agg);
    k_combine<<<NN * 4 / 256, 256, 0, stream>>>(agg, t2, dinv, b2);
    dim3 gg(ROWD / 64, KCHUNKS);
    k_gemmA<<<gg, 256, 0, stream>>>(t2, Wih, gxp);
    k_lstm<<<BATCH, 128, 0, stream>>>(gxp, Whh, bih, bhh, hseq);
    k_fc<<<2, 256, 0, stream>>>(hseq, Wfc1, bfc1, Wfc2, bfc2, out);
}